// Round 1
// baseline (4937.069 us; speedup 1.0000x reference)
//
#include <hip/hip_runtime.h>
#include <math.h>

// Problem constants (fixed by the reference)
#define NND 50000   // nodes
#define NED 600000  // edges
#define CD  128     // channels (in = hid = 128)
#define NG  64      // graphs

typedef short s8v  __attribute__((ext_vector_type(8)));   // 8 bf16 (raw bits) = 4 VGPRs
typedef float f4v  __attribute__((ext_vector_type(4)));   // MFMA accumulator
typedef unsigned short u16x4 __attribute__((ext_vector_type(4)));

static __device__ __forceinline__ unsigned short f2bf(float f) {
  union { float f; unsigned u; } v; v.f = f;
  unsigned r = v.u + 0x7fffu + ((v.u >> 16) & 1u);   // round-to-nearest-even
  return (unsigned short)(r >> 16);
}

// ---- degree / graph-size counting: one atomic per element ----
__global__ void count_k(const int* __restrict__ idx, float* __restrict__ cnt, int n) {
  int t = blockIdx.x * blockDim.x + threadIdx.x;
  if (t < n) atomicAdd(&cnt[idx[t]], 1.0f);
}

__global__ void inv_k(float* __restrict__ deg, int n) {
  int t = blockIdx.x * blockDim.x + threadIdx.x;
  if (t < n) deg[t] = 1.0f / fmaxf(deg[t], 1.0f);
}

// ---- fp32 -> bf16 conversion, optional per-node scale (mean divide) ----
__global__ void cvt_k(const float* __restrict__ in, const float* __restrict__ inv,
                      unsigned short* __restrict__ out) {
  int t = blockIdx.x * blockDim.x + threadIdx.x;   // one float4 chunk; NND*32 total
  if (t >= NND * 32) return;
  float s = inv ? inv[t >> 5] : 1.0f;
  float4 v = reinterpret_cast<const float4*>(in)[t];
  u16x4 o;
  o.x = f2bf(v.x * s); o.y = f2bf(v.y * s); o.z = f2bf(v.z * s); o.w = f2bf(v.w * s);
  reinterpret_cast<u16x4*>(out)[t] = o;
}

// ---- edge scatter: agg[dst] += x[src], 32 threads/edge, float4 + 4 atomics ----
__global__ void scatter_k(const float* __restrict__ x, const int* __restrict__ src,
                          const int* __restrict__ dst, float* __restrict__ agg) {
  int t = blockIdx.x * blockDim.x + threadIdx.x;
  if (t >= NED * 32) return;
  int e = t >> 5, q = t & 31;
  int s = src[e], d = dst[e];
  float4 v = reinterpret_cast<const float4*>(x + (size_t)s * CD)[q];
  float* a = agg + (size_t)d * CD + q * 4;
  atomicAdd(a + 0, v.x); atomicAdd(a + 1, v.y);
  atomicAdd(a + 2, v.z); atomicAdd(a + 3, v.w);
}

// ---- weight transpose+convert: WT[n*128+k] = bf16(W[k*128+n]) ----
__global__ void wcvt_k(const float* __restrict__ W, unsigned short* __restrict__ WT) {
  int t = blockIdx.x * blockDim.x + threadIdx.x;
  if (t >= CD * CD) return;
  int n = t >> 7, k = t & 127;
  WT[t] = f2bf(W[k * CD + n]);
}

// ---- fused: h = relu(ab @ Wl + xb @ Wr + bias); writes fp32 h and bf16 h ----
// Per block: 64 node rows x 128 cols. Per wave: 16 rows, 8 col-tiles of 16.
// MFMA 16x16x32 bf16; A frag: m=lane&15, k=quad*8+j; B frag from WT[n][k]:
// n=lane&15, k=quad*8+j; C/D: col=lane&15, row=quad*4+r (m89/m91-verified).
__global__ __launch_bounds__(256) void gemm_k(
    const unsigned short* __restrict__ ab, const unsigned short* __restrict__ xb,
    const unsigned short* __restrict__ WlT, const unsigned short* __restrict__ WrT,
    const float* __restrict__ bias, float* __restrict__ hf,
    unsigned short* __restrict__ hb) {
  const int wave = threadIdx.x >> 6;
  const int lane = threadIdx.x & 63;
  const int quad = lane >> 4;
  const int l16  = lane & 15;
  const int m0   = blockIdx.x * 64 + wave * 16;

  const int rowA  = m0 + l16;
  const int rowAc = rowA < NND ? rowA : NND - 1;   // clamp loads; stores are guarded

  s8v aA[4], aX[4];
#pragma unroll
  for (int kk = 0; kk < 4; ++kk) {
    size_t off = (size_t)rowAc * CD + kk * 32 + quad * 8;
    aA[kk] = *reinterpret_cast<const s8v*>(ab + off);
    aX[kk] = *reinterpret_cast<const s8v*>(xb + off);
  }

  f4v accL[8] = {};
  f4v accR[8] = {};

#pragma unroll
  for (int nt = 0; nt < 8; ++nt) {
    const int n = nt * 16 + l16;
#pragma unroll
    for (int kk = 0; kk < 4; ++kk) {
      size_t woff = (size_t)n * CD + kk * 32 + quad * 8;
      s8v bL = *reinterpret_cast<const s8v*>(WlT + woff);
      s8v bR = *reinterpret_cast<const s8v*>(WrT + woff);
      accL[nt] = __builtin_amdgcn_mfma_f32_16x16x32_bf16(aA[kk], bL, accL[nt], 0, 0, 0);
      accR[nt] = __builtin_amdgcn_mfma_f32_16x16x32_bf16(aX[kk], bR, accR[nt], 0, 0, 0);
    }
  }

#pragma unroll
  for (int nt = 0; nt < 8; ++nt) {
    const int col = nt * 16 + l16;
    const float bv = bias[col];
#pragma unroll
    for (int r = 0; r < 4; ++r) {
      int row = m0 + quad * 4 + r;
      if (row < NND) {
        float v = accL[nt][r] + accR[nt][r] + bv;
        v = fmaxf(v, 0.0f);
        hf[(size_t)row * CD + col] = v;
        hb[(size_t)row * CD + col] = f2bf(v);
      }
    }
  }
}

// ---- global mean pool (sum stage): atomics into pooled[g,c] ----
__global__ void pool_k(const float* __restrict__ h, const int* __restrict__ batch,
                       float* __restrict__ pooled) {
  int t = blockIdx.x * blockDim.x + threadIdx.x;
  if (t >= NND * 32) return;
  int node = t >> 5, q = t & 31;
  int g = batch[node];
  float4 v = reinterpret_cast<const float4*>(h)[t];
  float* p = pooled + (size_t)g * CD + q * 4;
  atomicAdd(p + 0, v.x); atomicAdd(p + 1, v.y);
  atomicAdd(p + 2, v.z); atomicAdd(p + 3, v.w);
}

// ---- classifier: out[g] = sigmoid(dot(pooled[g]/cnt, Wc) + bc) ----
__global__ void final_k(const float* __restrict__ pooled, const float* __restrict__ gcnt,
                        const float* __restrict__ Wc, const float* __restrict__ bc,
                        float* __restrict__ out) {
  int g = blockIdx.x;
  int lane = threadIdx.x;
  float part = pooled[g * CD + lane] * Wc[lane] +
               pooled[g * CD + 64 + lane] * Wc[64 + lane];
#pragma unroll
  for (int off = 32; off > 0; off >>= 1) part += __shfl_down(part, off, 64);
  if (lane == 0) {
    float z = part / fmaxf(gcnt[g], 1.0f) + bc[0];
    out[g] = 1.0f / (1.0f + expf(-z));
  }
}

extern "C" void kernel_launch(void* const* d_in, const int* in_sizes, int n_in,
                              void* d_out, int out_size, void* d_ws, size_t ws_size,
                              hipStream_t stream) {
  const float* x   = (const float*)d_in[0];
  const int*   ei  = (const int*)d_in[1];
  const int*   src = ei;             // edge_index[0]
  const int*   dst = ei + NED;       // edge_index[1]
  // d_in[2] = edge_weight: unused by the reference
  const int*   batch = (const int*)d_in[3];
  const float* Wl[4] = {(const float*)d_in[4],  (const float*)d_in[7],
                        (const float*)d_in[10], (const float*)d_in[13]};
  const float* Wr[4] = {(const float*)d_in[5],  (const float*)d_in[8],
                        (const float*)d_in[11], (const float*)d_in[14]};
  const float* bs[4] = {(const float*)d_in[6],  (const float*)d_in[9],
                        (const float*)d_in[12], (const float*)d_in[15]};
  const float* Wc = (const float*)d_in[16];
  const float* bc = (const float*)d_in[17];
  float* out = (float*)d_out;

  char* w = (char*)d_ws;
  auto alloc = [&](size_t bytes) {
    char* p = w; w += (bytes + 255) & ~(size_t)255; return p;
  };
  float* deg = (float*)alloc(NND * 4);                          // degree -> 1/max(deg,1)
  float* agg = (float*)alloc((size_t)NND * CD * 4);             // fp32 neighbor sums
  float* hA  = (float*)alloc((size_t)NND * CD * 4);             // fp32 layer features
  unsigned short* xb0 = (unsigned short*)alloc((size_t)NND * CD * 2);
  unsigned short* xb1 = (unsigned short*)alloc((size_t)NND * CD * 2);
  unsigned short* ab  = (unsigned short*)alloc((size_t)NND * CD * 2);
  unsigned short* WT[8];
  for (int i = 0; i < 8; ++i) WT[i] = (unsigned short*)alloc(CD * CD * 2);
  float* pooled = (float*)alloc(NG * CD * 4);
  float* gcnt   = (float*)alloc(NG * 4);

  hipMemsetAsync(deg, 0, NND * 4, stream);
  hipMemsetAsync(pooled, 0, NG * CD * 4, stream);
  hipMemsetAsync(gcnt, 0, NG * 4, stream);

  count_k<<<(NED + 255) / 256, 256, 0, stream>>>(dst, deg, NED);
  inv_k<<<(NND + 255) / 256, 256, 0, stream>>>(deg, NND);
  cvt_k<<<(NND * 32 + 255) / 256, 256, 0, stream>>>(x, nullptr, xb0);
  for (int l = 0; l < 4; ++l) {
    wcvt_k<<<64, 256, 0, stream>>>(Wl[l], WT[2 * l]);
    wcvt_k<<<64, 256, 0, stream>>>(Wr[l], WT[2 * l + 1]);
  }

  unsigned short* xcur = xb0;
  unsigned short* xnxt = xb1;
  for (int l = 0; l < 4; ++l) {
    hipMemsetAsync(agg, 0, (size_t)NND * CD * 4, stream);
    scatter_k<<<(NED * 32 + 255) / 256, 256, 0, stream>>>(l == 0 ? x : hA, src, dst, agg);
    cvt_k<<<(NND * 32 + 255) / 256, 256, 0, stream>>>(agg, deg, ab);  // mean + bf16
    gemm_k<<<(NND + 63) / 64, 256, 0, stream>>>(ab, xcur, WT[2 * l], WT[2 * l + 1],
                                                bs[l], hA, xnxt);
    unsigned short* t = xcur; xcur = xnxt; xnxt = t;
  }

  pool_k<<<(NND * 32 + 255) / 256, 256, 0, stream>>>(hA, batch, pooled);
  count_k<<<(NND + 255) / 256, 256, 0, stream>>>(batch, gcnt, NND);
  final_k<<<NG, 64, 0, stream>>>(pooled, gcnt, Wc, bc, out);
}

// Round 2
// 1012.388 us; speedup vs baseline: 4.8767x; 4.8767x over previous
//
#include <hip/hip_runtime.h>
#include <math.h>

// Problem constants (fixed by the reference)
#define NND 50000   // nodes
#define NED 600000  // edges
#define CD  128     // channels (in = hid = 128)
#define NG  64      // graphs

typedef short s8v  __attribute__((ext_vector_type(8)));   // 8 bf16 (raw bits) = 4 VGPRs
typedef float f4v  __attribute__((ext_vector_type(4)));   // MFMA accumulator
typedef unsigned short u16x4 __attribute__((ext_vector_type(4)));

static __device__ __forceinline__ unsigned short f2bf(float f) {
  union { float f; unsigned u; } v; v.f = f;
  unsigned r = v.u + 0x7fffu + ((v.u >> 16) & 1u);   // round-to-nearest-even
  return (unsigned short)(r >> 16);
}
static __device__ __forceinline__ float bf2f(unsigned short h) {
  union { unsigned u; float f; } v; v.u = ((unsigned)h) << 16; return v.f;
}

// ---- int degree count (CSR) ----
__global__ void counti_k(const int* __restrict__ idx, int* __restrict__ cnt, int n) {
  int t = blockIdx.x * blockDim.x + threadIdx.x;
  if (t < n) atomicAdd(&cnt[idx[t]], 1);
}

// ---- float count (graph sizes for mean pool) ----
__global__ void count_k(const int* __restrict__ idx, float* __restrict__ cnt, int n) {
  int t = blockIdx.x * blockDim.x + threadIdx.x;
  if (t < n) atomicAdd(&cnt[idx[t]], 1.0f);
}

// ---- single-block thread-coarse exclusive scan of cnt[NND] -> offs, cur ----
__global__ __launch_bounds__(1024) void scan_k(const int* __restrict__ cnt,
                                               int* __restrict__ offs,
                                               int* __restrict__ cur) {
  __shared__ int sums[1024];
  const int tid = threadIdx.x;
  const int CH = (NND + 1023) / 1024;   // 49 elements per thread
  const int base = tid * CH;
  int s = 0;
  for (int i = 0; i < CH; ++i) {
    int idx = base + i;
    if (idx < NND) s += cnt[idx];
  }
  sums[tid] = s;
  __syncthreads();
  for (int off = 1; off < 1024; off <<= 1) {   // inclusive Hillis-Steele
    int v = (tid >= off) ? sums[tid - off] : 0;
    __syncthreads();
    sums[tid] += v;
    __syncthreads();
  }
  int run = (tid == 0) ? 0 : sums[tid - 1];    // exclusive prefix for this chunk
  for (int i = 0; i < CH; ++i) {
    int idx = base + i;
    if (idx < NND) {
      offs[idx] = run;
      cur[idx]  = run;
      run += cnt[idx];
    }
  }
  if (tid == 1023) offs[NND] = sums[1022];     // total (thread 1023's chunk is empty)
}

// ---- CSR fill: csr[pos] = src for edges grouped by dst ----
__global__ void fill_k(const int* __restrict__ src, const int* __restrict__ dst,
                       int* __restrict__ cur, int* __restrict__ csr) {
  int e = blockIdx.x * blockDim.x + threadIdx.x;
  if (e >= NED) return;
  int d = dst[e];
  int pos = atomicAdd(&cur[d], 1);
  csr[pos] = src[e];
}

// ---- fp32 -> bf16 conversion (layer-0 input) ----
__global__ void cvt_k(const float* __restrict__ in, unsigned short* __restrict__ out) {
  int t = blockIdx.x * blockDim.x + threadIdx.x;   // one float4 chunk; NND*32 total
  if (t >= NND * 32) return;
  float4 v = reinterpret_cast<const float4*>(in)[t];
  u16x4 o;
  o.x = f2bf(v.x); o.y = f2bf(v.y); o.z = f2bf(v.z); o.w = f2bf(v.w);
  reinterpret_cast<u16x4*>(out)[t] = o;
}

// ---- CSR gather-reduce: ab[n] = bf16( mean_{e in in(n)} xb[csr[e]] ) ----
// One 32-lane team per dst node; lane owns 4 channels. Edge loop unrolled x4
// for 4 outstanding 8B gathers per team (latency hiding).
__global__ __launch_bounds__(256) void agg_k(const unsigned short* __restrict__ xb,
                                             const int* __restrict__ csr,
                                             const int* __restrict__ offs,
                                             unsigned short* __restrict__ ab) {
  const int team = (blockIdx.x * 256 + threadIdx.x) >> 5;   // == node id
  const int lane = threadIdx.x & 31;
  const int e0 = offs[team], e1 = offs[team + 1];
  const unsigned short* base = xb + lane * 4;
  float a0 = 0.f, a1 = 0.f, a2 = 0.f, a3 = 0.f;
  int e = e0;
  for (; e + 4 <= e1; e += 4) {
    int s0 = csr[e], s1 = csr[e + 1], s2 = csr[e + 2], s3 = csr[e + 3];
    u16x4 v0 = *reinterpret_cast<const u16x4*>(base + (size_t)s0 * CD);
    u16x4 v1 = *reinterpret_cast<const u16x4*>(base + (size_t)s1 * CD);
    u16x4 v2 = *reinterpret_cast<const u16x4*>(base + (size_t)s2 * CD);
    u16x4 v3 = *reinterpret_cast<const u16x4*>(base + (size_t)s3 * CD);
    a0 += bf2f(v0.x) + bf2f(v1.x) + bf2f(v2.x) + bf2f(v3.x);
    a1 += bf2f(v0.y) + bf2f(v1.y) + bf2f(v2.y) + bf2f(v3.y);
    a2 += bf2f(v0.z) + bf2f(v1.z) + bf2f(v2.z) + bf2f(v3.z);
    a3 += bf2f(v0.w) + bf2f(v1.w) + bf2f(v2.w) + bf2f(v3.w);
  }
  for (; e < e1; ++e) {
    int s0 = csr[e];
    u16x4 v0 = *reinterpret_cast<const u16x4*>(base + (size_t)s0 * CD);
    a0 += bf2f(v0.x); a1 += bf2f(v0.y); a2 += bf2f(v0.z); a3 += bf2f(v0.w);
  }
  const float invd = 1.0f / fmaxf((float)(e1 - e0), 1.0f);
  u16x4 o;
  o.x = f2bf(a0 * invd); o.y = f2bf(a1 * invd);
  o.z = f2bf(a2 * invd); o.w = f2bf(a3 * invd);
  *reinterpret_cast<u16x4*>(ab + (size_t)team * CD + lane * 4) = o;
}

// ---- weight transpose+convert: WT[n*128+k] = bf16(W[k*128+n]) ----
__global__ void wcvt_k(const float* __restrict__ W, unsigned short* __restrict__ WT) {
  int t = blockIdx.x * blockDim.x + threadIdx.x;
  if (t >= CD * CD) return;
  int n = t >> 7, k = t & 127;
  WT[t] = f2bf(W[k * CD + n]);
}

// ---- fused: h = relu(ab @ Wl + xb @ Wr + bias); writes fp32 h and bf16 h ----
// Per block: 64 node rows x 128 cols. Per wave: 16 rows, 8 col-tiles of 16.
// MFMA 16x16x32 bf16; A frag: m=lane&15, k=quad*8+j; B frag from WT[n][k]:
// n=lane&15, k=quad*8+j; C/D: col=lane&15, row=quad*4+r (m89/m91-verified).
__global__ __launch_bounds__(256) void gemm_k(
    const unsigned short* __restrict__ ab, const unsigned short* __restrict__ xb,
    const unsigned short* __restrict__ WlT, const unsigned short* __restrict__ WrT,
    const float* __restrict__ bias, float* __restrict__ hf,
    unsigned short* __restrict__ hb) {
  const int wave = threadIdx.x >> 6;
  const int lane = threadIdx.x & 63;
  const int quad = lane >> 4;
  const int l16  = lane & 15;
  const int m0   = blockIdx.x * 64 + wave * 16;

  const int rowA  = m0 + l16;
  const int rowAc = rowA < NND ? rowA : NND - 1;   // clamp loads; stores are guarded

  s8v aA[4], aX[4];
#pragma unroll
  for (int kk = 0; kk < 4; ++kk) {
    size_t off = (size_t)rowAc * CD + kk * 32 + quad * 8;
    aA[kk] = *reinterpret_cast<const s8v*>(ab + off);
    aX[kk] = *reinterpret_cast<const s8v*>(xb + off);
  }

  f4v accL[8] = {};
  f4v accR[8] = {};

#pragma unroll
  for (int nt = 0; nt < 8; ++nt) {
    const int n = nt * 16 + l16;
#pragma unroll
    for (int kk = 0; kk < 4; ++kk) {
      size_t woff = (size_t)n * CD + kk * 32 + quad * 8;
      s8v bL = *reinterpret_cast<const s8v*>(WlT + woff);
      s8v bR = *reinterpret_cast<const s8v*>(WrT + woff);
      accL[nt] = __builtin_amdgcn_mfma_f32_16x16x32_bf16(aA[kk], bL, accL[nt], 0, 0, 0);
      accR[nt] = __builtin_amdgcn_mfma_f32_16x16x32_bf16(aX[kk], bR, accR[nt], 0, 0, 0);
    }
  }

#pragma unroll
  for (int nt = 0; nt < 8; ++nt) {
    const int col = nt * 16 + l16;
    const float bv = bias[col];
#pragma unroll
    for (int r = 0; r < 4; ++r) {
      int row = m0 + quad * 4 + r;
      if (row < NND) {
        float v = accL[nt][r] + accR[nt][r] + bv;
        v = fmaxf(v, 0.0f);
        hf[(size_t)row * CD + col] = v;
        hb[(size_t)row * CD + col] = f2bf(v);
      }
    }
  }
}

// ---- segmented mean-pool stage 1: batch is SORTED, so walk contiguous rows
// and flush one atomic per graph boundary. thread owns one channel. ----
__global__ __launch_bounds__(256) void pool2_k(const float* __restrict__ h,
                                               const int* __restrict__ batch,
                                               float* __restrict__ pooled) {
  const int c    = threadIdx.x & 127;
  const int half = threadIdx.x >> 7;
  const int r0   = blockIdx.x * 512 + half * 256;
  float acc = 0.f;
  int gcur = -1;
  for (int i = 0; i < 256; ++i) {
    int row = r0 + i;
    if (row >= NND) break;
    int g = batch[row];
    if (g != gcur) {
      if (gcur >= 0) atomicAdd(&pooled[gcur * CD + c], acc);
      acc = 0.f; gcur = g;
    }
    acc += h[(size_t)row * CD + c];
  }
  if (gcur >= 0) atomicAdd(&pooled[gcur * CD + c], acc);
}

// ---- classifier: out[g] = sigmoid(dot(pooled[g]/cnt, Wc) + bc) ----
__global__ void final_k(const float* __restrict__ pooled, const float* __restrict__ gcnt,
                        const float* __restrict__ Wc, const float* __restrict__ bc,
                        float* __restrict__ out) {
  int g = blockIdx.x;
  int lane = threadIdx.x;
  float part = pooled[g * CD + lane] * Wc[lane] +
               pooled[g * CD + 64 + lane] * Wc[64 + lane];
#pragma unroll
  for (int off = 32; off > 0; off >>= 1) part += __shfl_down(part, off, 64);
  if (lane == 0) {
    float z = part / fmaxf(gcnt[g], 1.0f) + bc[0];
    out[g] = 1.0f / (1.0f + expf(-z));
  }
}

extern "C" void kernel_launch(void* const* d_in, const int* in_sizes, int n_in,
                              void* d_out, int out_size, void* d_ws, size_t ws_size,
                              hipStream_t stream) {
  const float* x   = (const float*)d_in[0];
  const int*   ei  = (const int*)d_in[1];
  const int*   src = ei;             // edge_index[0]
  const int*   dst = ei + NED;       // edge_index[1]
  // d_in[2] = edge_weight: unused by the reference
  const int*   batch = (const int*)d_in[3];
  const float* Wl[4] = {(const float*)d_in[4],  (const float*)d_in[7],
                        (const float*)d_in[10], (const float*)d_in[13]};
  const float* Wr[4] = {(const float*)d_in[5],  (const float*)d_in[8],
                        (const float*)d_in[11], (const float*)d_in[14]};
  const float* bs[4] = {(const float*)d_in[6],  (const float*)d_in[9],
                        (const float*)d_in[12], (const float*)d_in[15]};
  const float* Wc = (const float*)d_in[16];
  const float* bc = (const float*)d_in[17];
  float* out = (float*)d_out;

  char* w = (char*)d_ws;
  auto alloc = [&](size_t bytes) {
    char* p = w; w += (bytes + 255) & ~(size_t)255; return p;
  };
  int* cnti = (int*)alloc(NND * 4);
  int* offs = (int*)alloc((NND + 1) * 4);
  int* cur  = (int*)alloc(NND * 4);
  int* csr  = (int*)alloc((size_t)NED * 4);
  float* hA = (float*)alloc((size_t)NND * CD * 4);              // fp32 layer features
  unsigned short* xb0 = (unsigned short*)alloc((size_t)NND * CD * 2);
  unsigned short* xb1 = (unsigned short*)alloc((size_t)NND * CD * 2);
  unsigned short* ab  = (unsigned short*)alloc((size_t)NND * CD * 2);
  unsigned short* WT[8];
  for (int i = 0; i < 8; ++i) WT[i] = (unsigned short*)alloc(CD * CD * 2);
  float* pooled = (float*)alloc(NG * CD * 4);
  float* gcnt   = (float*)alloc(NG * 4);

  hipMemsetAsync(cnti, 0, NND * 4, stream);
  hipMemsetAsync(pooled, 0, NG * CD * 4, stream);
  hipMemsetAsync(gcnt, 0, NG * 4, stream);

  // CSR build (per call; inputs are restored before every timed launch)
  counti_k<<<(NED + 255) / 256, 256, 0, stream>>>(dst, cnti, NED);
  scan_k<<<1, 1024, 0, stream>>>(cnti, offs, cur);
  fill_k<<<(NED + 255) / 256, 256, 0, stream>>>(src, dst, cur, csr);

  cvt_k<<<(NND * 32 + 255) / 256, 256, 0, stream>>>(x, xb0);
  for (int l = 0; l < 4; ++l) {
    wcvt_k<<<64, 256, 0, stream>>>(Wl[l], WT[2 * l]);
    wcvt_k<<<64, 256, 0, stream>>>(Wr[l], WT[2 * l + 1]);
  }

  unsigned short* xcur = xb0;
  unsigned short* xnxt = xb1;
  for (int l = 0; l < 4; ++l) {
    agg_k<<<(NND + 7) / 8, 256, 0, stream>>>(xcur, csr, offs, ab);
    gemm_k<<<(NND + 63) / 64, 256, 0, stream>>>(ab, xcur, WT[2 * l], WT[2 * l + 1],
                                                bs[l], hA, xnxt);
    unsigned short* t = xcur; xcur = xnxt; xnxt = t;
  }

  pool2_k<<<(NND + 511) / 512, 256, 0, stream>>>(hA, batch, pooled);
  count_k<<<(NND + 255) / 256, 256, 0, stream>>>(batch, gcnt, NND);
  final_k<<<NG, 64, 0, stream>>>(pooled, gcnt, Wc, bc, out);
}

// Round 3
// 701.196 us; speedup vs baseline: 7.0409x; 1.4438x over previous
//
#include <hip/hip_runtime.h>
#include <math.h>

// Problem constants (fixed by the reference)
#define NND 50000   // nodes
#define NED 600000  // edges
#define CD  128     // channels (in = hid = 128)
#define NG  64      // graphs

typedef short s8v  __attribute__((ext_vector_type(8)));   // 8 bf16 (raw bits) = 4 VGPRs
typedef float f4v  __attribute__((ext_vector_type(4)));   // MFMA accumulator
typedef unsigned short u16x4 __attribute__((ext_vector_type(4)));

static __device__ __forceinline__ unsigned short f2bf(float f) {
  union { float f; unsigned u; } v; v.f = f;
  unsigned r = v.u + 0x7fffu + ((v.u >> 16) & 1u);   // round-to-nearest-even
  return (unsigned short)(r >> 16);
}
static __device__ __forceinline__ float bf2f(unsigned short h) {
  union { unsigned u; float f; } v; v.u = ((unsigned)h) << 16; return v.f;
}

// ---- int degree count (CSR) ----
__global__ void counti_k(const int* __restrict__ idx, int* __restrict__ cnt, int n) {
  int t = blockIdx.x * blockDim.x + threadIdx.x;
  if (t < n) atomicAdd(&cnt[idx[t]], 1);
}

// ---- graph boundaries via binary search in SORTED batch: gb[g] = lower_bound(g) ----
__global__ void bounds_k(const int* __restrict__ batch, int* __restrict__ gb) {
  int g = threadIdx.x;
  if (g > NG) return;
  int lo = 0, hi = NND;
  while (lo < hi) {
    int mid = (lo + hi) >> 1;
    if (batch[mid] < g) lo = mid + 1; else hi = mid;
  }
  gb[g] = lo;
}

// ---- single-block thread-coarse exclusive scan of cnt[NND] -> offs, cur ----
__global__ __launch_bounds__(1024) void scan_k(const int* __restrict__ cnt,
                                               int* __restrict__ offs,
                                               int* __restrict__ cur) {
  __shared__ int sums[1024];
  const int tid = threadIdx.x;
  const int CH = (NND + 1023) / 1024;   // 49 elements per thread
  const int base = tid * CH;
  int s = 0;
  for (int i = 0; i < CH; ++i) {
    int idx = base + i;
    if (idx < NND) s += cnt[idx];
  }
  sums[tid] = s;
  __syncthreads();
  for (int off = 1; off < 1024; off <<= 1) {   // inclusive Hillis-Steele
    int v = (tid >= off) ? sums[tid - off] : 0;
    __syncthreads();
    sums[tid] += v;
    __syncthreads();
  }
  int run = (tid == 0) ? 0 : sums[tid - 1];    // exclusive prefix for this chunk
  for (int i = 0; i < CH; ++i) {
    int idx = base + i;
    if (idx < NND) {
      offs[idx] = run;
      cur[idx]  = run;
      run += cnt[idx];
    }
  }
  if (tid == 1023) offs[NND] = sums[1022];     // total (thread 1023's chunk is empty)
}

// ---- CSR fill: csr[pos] = src for edges grouped by dst ----
__global__ void fill_k(const int* __restrict__ src, const int* __restrict__ dst,
                       int* __restrict__ cur, int* __restrict__ csr) {
  int e = blockIdx.x * blockDim.x + threadIdx.x;
  if (e >= NED) return;
  int d = dst[e];
  int pos = atomicAdd(&cur[d], 1);
  csr[pos] = src[e];
}

// ---- fp32 -> bf16 conversion (layer-0 input) ----
__global__ void cvt_k(const float* __restrict__ in, unsigned short* __restrict__ out) {
  int t = blockIdx.x * blockDim.x + threadIdx.x;   // one float4 chunk; NND*32 total
  if (t >= NND * 32) return;
  float4 v = reinterpret_cast<const float4*>(in)[t];
  u16x4 o;
  o.x = f2bf(v.x); o.y = f2bf(v.y); o.z = f2bf(v.z); o.w = f2bf(v.w);
  reinterpret_cast<u16x4*>(out)[t] = o;
}

// ---- all 8 weight transposes+converts in ONE launch: WT[n*128+k]=bf16(W[k*128+n]) ----
struct WPtrs { const float* w[8]; unsigned short* wt[8]; };
__global__ void wcvt8_k(WPtrs p) {
  int t = blockIdx.x * blockDim.x + threadIdx.x;   // 8 * 16384 total
  if (t >= 8 * CD * CD) return;
  int m = t >> 14, r = t & (CD * CD - 1);
  int n = r >> 7, k = r & 127;
  p.wt[m][r] = f2bf(p.w[m][k * CD + n]);
}

// ---- CSR gather-reduce: ab[n] = bf16( mean_{e in in(n)} xb[csr[e]] ) ----
// One 32-lane team per dst node; lane owns 4 channels. Edge loop unrolled x4
// for 4 outstanding 8B gathers per team (latency hiding).
__global__ __launch_bounds__(256) void agg_k(const unsigned short* __restrict__ xb,
                                             const int* __restrict__ csr,
                                             const int* __restrict__ offs,
                                             unsigned short* __restrict__ ab) {
  const int team = (blockIdx.x * 256 + threadIdx.x) >> 5;   // == node id
  const int lane = threadIdx.x & 31;
  const int e0 = offs[team], e1 = offs[team + 1];
  const unsigned short* base = xb + lane * 4;
  float a0 = 0.f, a1 = 0.f, a2 = 0.f, a3 = 0.f;
  int e = e0;
  for (; e + 4 <= e1; e += 4) {
    int s0 = csr[e], s1 = csr[e + 1], s2 = csr[e + 2], s3 = csr[e + 3];
    u16x4 v0 = *reinterpret_cast<const u16x4*>(base + (size_t)s0 * CD);
    u16x4 v1 = *reinterpret_cast<const u16x4*>(base + (size_t)s1 * CD);
    u16x4 v2 = *reinterpret_cast<const u16x4*>(base + (size_t)s2 * CD);
    u16x4 v3 = *reinterpret_cast<const u16x4*>(base + (size_t)s3 * CD);
    a0 += bf2f(v0.x) + bf2f(v1.x) + bf2f(v2.x) + bf2f(v3.x);
    a1 += bf2f(v0.y) + bf2f(v1.y) + bf2f(v2.y) + bf2f(v3.y);
    a2 += bf2f(v0.z) + bf2f(v1.z) + bf2f(v2.z) + bf2f(v3.z);
    a3 += bf2f(v0.w) + bf2f(v1.w) + bf2f(v2.w) + bf2f(v3.w);
  }
  for (; e < e1; ++e) {
    int s0 = csr[e];
    u16x4 v0 = *reinterpret_cast<const u16x4*>(base + (size_t)s0 * CD);
    a0 += bf2f(v0.x); a1 += bf2f(v0.y); a2 += bf2f(v0.z); a3 += bf2f(v0.w);
  }
  const float invd = 1.0f / fmaxf((float)(e1 - e0), 1.0f);
  u16x4 o;
  o.x = f2bf(a0 * invd); o.y = f2bf(a1 * invd);
  o.z = f2bf(a2 * invd); o.w = f2bf(a3 * invd);
  *reinterpret_cast<u16x4*>(ab + (size_t)team * CD + lane * 4) = o;
}

// ---- fused: h = relu(ab @ Wl + xb @ Wr + bias); writes fp32 h and bf16 h ----
// Per block: 64 node rows x 128 cols. Per wave: 16 rows, 8 col-tiles of 16.
// MFMA 16x16x32 bf16; A frag: m=lane&15, k=quad*8+j; B frag from WT[n][k]:
// n=lane&15, k=quad*8+j; C/D: col=lane&15, row=quad*4+r (m89/m91-verified).
__global__ __launch_bounds__(256) void gemm_k(
    const unsigned short* __restrict__ ab, const unsigned short* __restrict__ xb,
    const unsigned short* __restrict__ WlT, const unsigned short* __restrict__ WrT,
    const float* __restrict__ bias, float* __restrict__ hf,
    unsigned short* __restrict__ hb) {
  const int wave = threadIdx.x >> 6;
  const int lane = threadIdx.x & 63;
  const int quad = lane >> 4;
  const int l16  = lane & 15;
  const int m0   = blockIdx.x * 64 + wave * 16;

  const int rowA  = m0 + l16;
  const int rowAc = rowA < NND ? rowA : NND - 1;   // clamp loads; stores are guarded

  s8v aA[4], aX[4];
#pragma unroll
  for (int kk = 0; kk < 4; ++kk) {
    size_t off = (size_t)rowAc * CD + kk * 32 + quad * 8;
    aA[kk] = *reinterpret_cast<const s8v*>(ab + off);
    aX[kk] = *reinterpret_cast<const s8v*>(xb + off);
  }

  f4v accL[8] = {};
  f4v accR[8] = {};

#pragma unroll
  for (int nt = 0; nt < 8; ++nt) {
    const int n = nt * 16 + l16;
#pragma unroll
    for (int kk = 0; kk < 4; ++kk) {
      size_t woff = (size_t)n * CD + kk * 32 + quad * 8;
      s8v bL = *reinterpret_cast<const s8v*>(WlT + woff);
      s8v bR = *reinterpret_cast<const s8v*>(WrT + woff);
      accL[nt] = __builtin_amdgcn_mfma_f32_16x16x32_bf16(aA[kk], bL, accL[nt], 0, 0, 0);
      accR[nt] = __builtin_amdgcn_mfma_f32_16x16x32_bf16(aX[kk], bR, accR[nt], 0, 0, 0);
    }
  }

#pragma unroll
  for (int nt = 0; nt < 8; ++nt) {
    const int col = nt * 16 + l16;
    const float bv = bias[col];
#pragma unroll
    for (int r = 0; r < 4; ++r) {
      int row = m0 + quad * 4 + r;
      if (row < NND) {
        float v = accL[nt][r] + accR[nt][r] + bv;
        v = fmaxf(v, 0.0f);
        hf[(size_t)row * CD + col] = v;
        hb[(size_t)row * CD + col] = f2bf(v);
      }
    }
  }
}

// ---- segmented mean-pool stage 1: batch is SORTED, so walk contiguous rows
// and flush one atomic per graph boundary. thread owns one channel. ----
__global__ __launch_bounds__(256) void pool2_k(const float* __restrict__ h,
                                               const int* __restrict__ batch,
                                               float* __restrict__ pooled) {
  const int c    = threadIdx.x & 127;
  const int half = threadIdx.x >> 7;
  const int r0   = blockIdx.x * 512 + half * 256;
  float acc = 0.f;
  int gcur = -1;
  for (int i = 0; i < 256; ++i) {
    int row = r0 + i;
    if (row >= NND) break;
    int g = batch[row];
    if (g != gcur) {
      if (gcur >= 0) atomicAdd(&pooled[gcur * CD + c], acc);
      acc = 0.f; gcur = g;
    }
    acc += h[(size_t)row * CD + c];
  }
  if (gcur >= 0) atomicAdd(&pooled[gcur * CD + c], acc);
}

// ---- classifier: out[g] = sigmoid(dot(pooled[g]/cnt, Wc) + bc) ----
__global__ void final_k(const float* __restrict__ pooled, const int* __restrict__ gb,
                        const float* __restrict__ Wc, const float* __restrict__ bc,
                        float* __restrict__ out) {
  int g = blockIdx.x;
  int lane = threadIdx.x;
  float part = pooled[g * CD + lane] * Wc[lane] +
               pooled[g * CD + 64 + lane] * Wc[64 + lane];
#pragma unroll
  for (int off = 32; off > 0; off >>= 1) part += __shfl_down(part, off, 64);
  if (lane == 0) {
    float cnt = (float)(gb[g + 1] - gb[g]);
    float z = part / fmaxf(cnt, 1.0f) + bc[0];
    out[g] = 1.0f / (1.0f + expf(-z));
  }
}

extern "C" void kernel_launch(void* const* d_in, const int* in_sizes, int n_in,
                              void* d_out, int out_size, void* d_ws, size_t ws_size,
                              hipStream_t stream) {
  const float* x   = (const float*)d_in[0];
  const int*   ei  = (const int*)d_in[1];
  const int*   src = ei;             // edge_index[0]
  const int*   dst = ei + NED;       // edge_index[1]
  // d_in[2] = edge_weight: unused by the reference
  const int*   batch = (const int*)d_in[3];
  const float* Wc = (const float*)d_in[16];
  const float* bc = (const float*)d_in[17];
  float* out = (float*)d_out;

  char* w = (char*)d_ws;
  auto alloc = [&](size_t bytes) {
    char* p = w; w += (bytes + 255) & ~(size_t)255; return p;
  };
  int* cnti = (int*)alloc(NND * 4);
  int* offs = (int*)alloc((NND + 1) * 4);
  int* cur  = (int*)alloc(NND * 4);
  int* csr  = (int*)alloc((size_t)NED * 4);
  int* gb   = (int*)alloc((NG + 1) * 4);
  float* hA = (float*)alloc((size_t)NND * CD * 4);              // fp32 layer features
  unsigned short* xb0 = (unsigned short*)alloc((size_t)NND * CD * 2);
  unsigned short* xb1 = (unsigned short*)alloc((size_t)NND * CD * 2);
  unsigned short* ab  = (unsigned short*)alloc((size_t)NND * CD * 2);
  WPtrs wp;
  for (int i = 0; i < 4; ++i) {
    wp.w[2 * i]     = (const float*)d_in[4 + 3 * i];      // Wl{i+1}
    wp.w[2 * i + 1] = (const float*)d_in[5 + 3 * i];      // Wr{i+1}
  }
  for (int i = 0; i < 8; ++i) wp.wt[i] = (unsigned short*)alloc(CD * CD * 2);
  const float* bs[4] = {(const float*)d_in[6],  (const float*)d_in[9],
                        (const float*)d_in[12], (const float*)d_in[15]};
  float* pooled = (float*)alloc(NG * CD * 4);

  hipMemsetAsync(cnti, 0, NND * 4, stream);
  hipMemsetAsync(pooled, 0, NG * CD * 4, stream);

  // CSR build (per call; inputs are restored before every timed launch)
  counti_k<<<(NED + 255) / 256, 256, 0, stream>>>(dst, cnti, NED);
  scan_k<<<1, 1024, 0, stream>>>(cnti, offs, cur);
  fill_k<<<(NED + 255) / 256, 256, 0, stream>>>(src, dst, cur, csr);
  bounds_k<<<1, 128, 0, stream>>>(batch, gb);

  cvt_k<<<(NND * 32 + 255) / 256, 256, 0, stream>>>(x, xb0);
  wcvt8_k<<<(8 * CD * CD + 255) / 256, 256, 0, stream>>>(wp);

  unsigned short* xcur = xb0;
  unsigned short* xnxt = xb1;
  for (int l = 0; l < 4; ++l) {
    agg_k<<<(NND + 7) / 8, 256, 0, stream>>>(xcur, csr, offs, ab);
    gemm_k<<<(NND + 63) / 64, 256, 0, stream>>>(ab, xcur, wp.wt[2 * l], wp.wt[2 * l + 1],
                                                bs[l], hA, xnxt);
    unsigned short* t = xcur; xcur = xnxt; xnxt = t;
  }

  pool2_k<<<(NND + 511) / 512, 256, 0, stream>>>(hA, batch, pooled);
  final_k<<<NG, 64, 0, stream>>>(pooled, gb, Wc, bc, out);
}

// Round 4
// 570.724 us; speedup vs baseline: 8.6505x; 1.2286x over previous
//
#include <hip/hip_runtime.h>
#include <math.h>

// Problem constants (fixed by the reference)
#define NND 50000   // nodes
#define NED 600000  // edges
#define CD  128     // channels (in = hid = 128)
#define NG  64      // graphs

typedef short s8v  __attribute__((ext_vector_type(8)));   // 8 bf16 (raw bits) = 4 VGPRs
typedef float f4v  __attribute__((ext_vector_type(4)));   // MFMA accumulator
typedef unsigned short u16x4 __attribute__((ext_vector_type(4)));

static __device__ __forceinline__ unsigned short f2bf(float f) {
  union { float f; unsigned u; } v; v.f = f;
  unsigned r = v.u + 0x7fffu + ((v.u >> 16) & 1u);   // round-to-nearest-even
  return (unsigned short)(r >> 16);
}
static __device__ __forceinline__ float bf2f(unsigned short h) {
  union { unsigned u; float f; } v; v.u = ((unsigned)h) << 16; return v.f;
}

// ---- int degree count (CSR) ----
__global__ void counti_k(const int* __restrict__ idx, int* __restrict__ cnt, int n) {
  int t = blockIdx.x * blockDim.x + threadIdx.x;
  if (t < n) atomicAdd(&cnt[idx[t]], 1);
}

// ---- graph boundaries via binary search in SORTED batch: gb[g] = lower_bound(g) ----
__global__ void bounds_k(const int* __restrict__ batch, int* __restrict__ gb) {
  int g = threadIdx.x;
  if (g > NG) return;
  int lo = 0, hi = NND;
  while (lo < hi) {
    int mid = (lo + hi) >> 1;
    if (batch[mid] < g) lo = mid + 1; else hi = mid;
  }
  gb[g] = lo;
}

// ---- single-block thread-coarse exclusive scan of cnt[NND] -> offs, cur ----
__global__ __launch_bounds__(1024) void scan_k(const int* __restrict__ cnt,
                                               int* __restrict__ offs,
                                               int* __restrict__ cur) {
  __shared__ int sums[1024];
  const int tid = threadIdx.x;
  const int CH = (NND + 1023) / 1024;   // 49 elements per thread
  const int base = tid * CH;
  int s = 0;
  for (int i = 0; i < CH; ++i) {
    int idx = base + i;
    if (idx < NND) s += cnt[idx];
  }
  sums[tid] = s;
  __syncthreads();
  for (int off = 1; off < 1024; off <<= 1) {   // inclusive Hillis-Steele
    int v = (tid >= off) ? sums[tid - off] : 0;
    __syncthreads();
    sums[tid] += v;
    __syncthreads();
  }
  int run = (tid == 0) ? 0 : sums[tid - 1];    // exclusive prefix for this chunk
  for (int i = 0; i < CH; ++i) {
    int idx = base + i;
    if (idx < NND) {
      offs[idx] = run;
      cur[idx]  = run;
      run += cnt[idx];
    }
  }
  if (tid == 1023) offs[NND] = sums[1022];     // total (thread 1023's chunk is empty)
}

// ---- CSR fill: csr[pos] = src for edges grouped by dst ----
__global__ void fill_k(const int* __restrict__ src, const int* __restrict__ dst,
                       int* __restrict__ cur, int* __restrict__ csr) {
  int e = blockIdx.x * blockDim.x + threadIdx.x;
  if (e >= NED) return;
  int d = dst[e];
  int pos = atomicAdd(&cur[d], 1);
  csr[pos] = src[e];
}

// ---- fp32 -> bf16 conversion (layer-0 input) ----
__global__ void cvt_k(const float* __restrict__ in, unsigned short* __restrict__ out) {
  int t = blockIdx.x * blockDim.x + threadIdx.x;   // one float4 chunk; NND*32 total
  if (t >= NND * 32) return;
  float4 v = reinterpret_cast<const float4*>(in)[t];
  u16x4 o;
  o.x = f2bf(v.x); o.y = f2bf(v.y); o.z = f2bf(v.z); o.w = f2bf(v.w);
  reinterpret_cast<u16x4*>(out)[t] = o;
}

// ---- all 8 weight transposes+converts in ONE launch: WT[n*128+k]=bf16(W[k*128+n]) ----
struct WPtrs { const float* w[8]; unsigned short* wt[8]; };
__global__ void wcvt8_k(WPtrs p) {
  int t = blockIdx.x * blockDim.x + threadIdx.x;   // 8 * 16384 total
  if (t >= 8 * CD * CD) return;
  int m = t >> 14, r = t & (CD * CD - 1);
  int n = r >> 7, k = r & 127;
  p.wt[m][r] = f2bf(p.w[m][k * CD + n]);
}

// ---- CSR gather-reduce: ab[n] = bf16( mean_{e in in(n)} xb[csr[e]] ) ----
// One 32-lane team per dst node; lane owns 4 channels. Edge loop unrolled x4
// for 4 outstanding 8B gathers per team (latency hiding).
__global__ __launch_bounds__(256) void agg_k(const unsigned short* __restrict__ xb,
                                             const int* __restrict__ csr,
                                             const int* __restrict__ offs,
                                             unsigned short* __restrict__ ab) {
  const int team = (blockIdx.x * 256 + threadIdx.x) >> 5;   // == node id
  const int lane = threadIdx.x & 31;
  const int e0 = offs[team], e1 = offs[team + 1];
  const unsigned short* base = xb + lane * 4;
  float a0 = 0.f, a1 = 0.f, a2 = 0.f, a3 = 0.f;
  int e = e0;
  for (; e + 4 <= e1; e += 4) {
    int s0 = csr[e], s1 = csr[e + 1], s2 = csr[e + 2], s3 = csr[e + 3];
    u16x4 v0 = *reinterpret_cast<const u16x4*>(base + (size_t)s0 * CD);
    u16x4 v1 = *reinterpret_cast<const u16x4*>(base + (size_t)s1 * CD);
    u16x4 v2 = *reinterpret_cast<const u16x4*>(base + (size_t)s2 * CD);
    u16x4 v3 = *reinterpret_cast<const u16x4*>(base + (size_t)s3 * CD);
    a0 += bf2f(v0.x) + bf2f(v1.x) + bf2f(v2.x) + bf2f(v3.x);
    a1 += bf2f(v0.y) + bf2f(v1.y) + bf2f(v2.y) + bf2f(v3.y);
    a2 += bf2f(v0.z) + bf2f(v1.z) + bf2f(v2.z) + bf2f(v3.z);
    a3 += bf2f(v0.w) + bf2f(v1.w) + bf2f(v2.w) + bf2f(v3.w);
  }
  for (; e < e1; ++e) {
    int s0 = csr[e];
    u16x4 v0 = *reinterpret_cast<const u16x4*>(base + (size_t)s0 * CD);
    a0 += bf2f(v0.x); a1 += bf2f(v0.y); a2 += bf2f(v0.z); a3 += bf2f(v0.w);
  }
  const float invd = 1.0f / fmaxf((float)(e1 - e0), 1.0f);
  u16x4 o;
  o.x = f2bf(a0 * invd); o.y = f2bf(a1 * invd);
  o.z = f2bf(a2 * invd); o.w = f2bf(a3 * invd);
  *reinterpret_cast<u16x4*>(ab + (size_t)team * CD + lane * 4) = o;
}

// ---- fused: h = relu(ab @ Wl + xb @ Wr + bias); writes fp32 h and bf16 h ----
// Per block: 64 node rows x 128 cols. Per wave: 16 rows, 8 col-tiles of 16.
// MFMA 16x16x32 bf16; A frag: m=lane&15, k=quad*8+j; B frag from WT[n][k]:
// n=lane&15, k=quad*8+j; C/D: col=lane&15, row=quad*4+r (m89/m91-verified).
__global__ __launch_bounds__(256) void gemm_k(
    const unsigned short* __restrict__ ab, const unsigned short* __restrict__ xb,
    const unsigned short* __restrict__ WlT, const unsigned short* __restrict__ WrT,
    const float* __restrict__ bias, float* __restrict__ hf,
    unsigned short* __restrict__ hb) {
  const int wave = threadIdx.x >> 6;
  const int lane = threadIdx.x & 63;
  const int quad = lane >> 4;
  const int l16  = lane & 15;
  const int m0   = blockIdx.x * 64 + wave * 16;

  const int rowA  = m0 + l16;
  const int rowAc = rowA < NND ? rowA : NND - 1;   // clamp loads; stores are guarded

  s8v aA[4], aX[4];
#pragma unroll
  for (int kk = 0; kk < 4; ++kk) {
    size_t off = (size_t)rowAc * CD + kk * 32 + quad * 8;
    aA[kk] = *reinterpret_cast<const s8v*>(ab + off);
    aX[kk] = *reinterpret_cast<const s8v*>(xb + off);
  }

  f4v accL[8] = {};
  f4v accR[8] = {};

#pragma unroll
  for (int nt = 0; nt < 8; ++nt) {
    const int n = nt * 16 + l16;
#pragma unroll
    for (int kk = 0; kk < 4; ++kk) {
      size_t woff = (size_t)n * CD + kk * 32 + quad * 8;
      s8v bL = *reinterpret_cast<const s8v*>(WlT + woff);
      s8v bR = *reinterpret_cast<const s8v*>(WrT + woff);
      accL[nt] = __builtin_amdgcn_mfma_f32_16x16x32_bf16(aA[kk], bL, accL[nt], 0, 0, 0);
      accR[nt] = __builtin_amdgcn_mfma_f32_16x16x32_bf16(aX[kk], bR, accR[nt], 0, 0, 0);
    }
  }

#pragma unroll
  for (int nt = 0; nt < 8; ++nt) {
    const int col = nt * 16 + l16;
    const float bv = bias[col];
#pragma unroll
    for (int r = 0; r < 4; ++r) {
      int row = m0 + quad * 4 + r;
      if (row < NND) {
        float v = accL[nt][r] + accR[nt][r] + bv;
        v = fmaxf(v, 0.0f);
        hf[(size_t)row * CD + col] = v;
        hb[(size_t)row * CD + col] = f2bf(v);
      }
    }
  }
}

// ---- mean-pool: 32-row chunks, one thread per channel, boundary-flush atomics.
// batch is SORTED; common case = whole chunk inside one graph (branch-free sum). ----
__global__ __launch_bounds__(128) void pool3_k(const float* __restrict__ h,
                                               const int* __restrict__ batch,
                                               float* __restrict__ pooled) {
  const int c  = threadIdx.x;
  const int r0 = blockIdx.x * 32;
  const int rend = (r0 + 32 < NND) ? r0 + 32 : NND;
  const int g0 = batch[r0];
  const int g1 = batch[rend - 1];
  if (g0 == g1) {
    float acc = 0.f;
#pragma unroll
    for (int i = 0; i < 32; ++i) {
      int row = r0 + i;
      if (row < rend) acc += h[(size_t)row * CD + c];
    }
    atomicAdd(&pooled[g0 * CD + c], acc);
  } else {
    float acc = 0.f;
    int gcur = g0;
    for (int row = r0; row < rend; ++row) {
      int g = batch[row];
      if (g != gcur) {
        atomicAdd(&pooled[gcur * CD + c], acc);
        acc = 0.f; gcur = g;
      }
      acc += h[(size_t)row * CD + c];
    }
    atomicAdd(&pooled[gcur * CD + c], acc);
  }
}

// ---- classifier: out[g] = sigmoid(dot(pooled[g]/cnt, Wc) + bc) ----
__global__ void final_k(const float* __restrict__ pooled, const int* __restrict__ gb,
                        const float* __restrict__ Wc, const float* __restrict__ bc,
                        float* __restrict__ out) {
  int g = blockIdx.x;
  int lane = threadIdx.x;
  float part = pooled[g * CD + lane] * Wc[lane] +
               pooled[g * CD + 64 + lane] * Wc[64 + lane];
#pragma unroll
  for (int off = 32; off > 0; off >>= 1) part += __shfl_down(part, off, 64);
  if (lane == 0) {
    float cnt = (float)(gb[g + 1] - gb[g]);
    float z = part / fmaxf(cnt, 1.0f) + bc[0];
    out[g] = 1.0f / (1.0f + expf(-z));
  }
}

extern "C" void kernel_launch(void* const* d_in, const int* in_sizes, int n_in,
                              void* d_out, int out_size, void* d_ws, size_t ws_size,
                              hipStream_t stream) {
  const float* x   = (const float*)d_in[0];
  const int*   ei  = (const int*)d_in[1];
  const int*   src = ei;             // edge_index[0]
  const int*   dst = ei + NED;       // edge_index[1]
  // d_in[2] = edge_weight: unused by the reference
  const int*   batch = (const int*)d_in[3];
  const float* Wc = (const float*)d_in[16];
  const float* bc = (const float*)d_in[17];
  float* out = (float*)d_out;

  char* w = (char*)d_ws;
  auto alloc = [&](size_t bytes) {
    char* p = w; w += (bytes + 255) & ~(size_t)255; return p;
  };
  int* cnti = (int*)alloc(NND * 4);
  int* offs = (int*)alloc((NND + 1) * 4);
  int* cur  = (int*)alloc(NND * 4);
  int* csr  = (int*)alloc((size_t)NED * 4);
  int* gb   = (int*)alloc((NG + 1) * 4);
  float* hA = (float*)alloc((size_t)NND * CD * 4);              // fp32 layer features
  unsigned short* xb0 = (unsigned short*)alloc((size_t)NND * CD * 2);
  unsigned short* xb1 = (unsigned short*)alloc((size_t)NND * CD * 2);
  unsigned short* ab  = (unsigned short*)alloc((size_t)NND * CD * 2);
  WPtrs wp;
  for (int i = 0; i < 4; ++i) {
    wp.w[2 * i]     = (const float*)d_in[4 + 3 * i];      // Wl{i+1}
    wp.w[2 * i + 1] = (const float*)d_in[5 + 3 * i];      // Wr{i+1}
  }
  for (int i = 0; i < 8; ++i) wp.wt[i] = (unsigned short*)alloc(CD * CD * 2);
  const float* bs[4] = {(const float*)d_in[6],  (const float*)d_in[9],
                        (const float*)d_in[12], (const float*)d_in[15]};
  float* pooled = (float*)alloc(NG * CD * 4);

  hipMemsetAsync(cnti, 0, NND * 4, stream);
  hipMemsetAsync(pooled, 0, NG * CD * 4, stream);

  // CSR build (per call; inputs are restored before every timed launch)
  counti_k<<<(NED + 255) / 256, 256, 0, stream>>>(dst, cnti, NED);
  scan_k<<<1, 1024, 0, stream>>>(cnti, offs, cur);
  fill_k<<<(NED + 255) / 256, 256, 0, stream>>>(src, dst, cur, csr);
  bounds_k<<<1, 128, 0, stream>>>(batch, gb);

  cvt_k<<<(NND * 32 + 255) / 256, 256, 0, stream>>>(x, xb0);
  wcvt8_k<<<(8 * CD * CD + 255) / 256, 256, 0, stream>>>(wp);

  unsigned short* xcur = xb0;
  unsigned short* xnxt = xb1;
  for (int l = 0; l < 4; ++l) {
    agg_k<<<(NND + 7) / 8, 256, 0, stream>>>(xcur, csr, offs, ab);
    gemm_k<<<(NND + 63) / 64, 256, 0, stream>>>(ab, xcur, wp.wt[2 * l], wp.wt[2 * l + 1],
                                                bs[l], hA, xnxt);
    unsigned short* t = xcur; xcur = xnxt; xnxt = t;
  }

  pool3_k<<<(NND + 31) / 32, 128, 0, stream>>>(hA, batch, pooled);
  final_k<<<NG, 64, 0, stream>>>(pooled, gb, Wc, bc, out);
}

// Round 5
// 455.856 us; speedup vs baseline: 10.8303x; 1.2520x over previous
//
#include <hip/hip_runtime.h>
#include <math.h>

// Problem constants (fixed by the reference)
#define NND 50000   // nodes
#define NED 600000  // edges
#define CD  128     // channels (in = hid = 128)
#define NG  64      // graphs
#define NBLK 196    // ceil(NND/256) scan blocks

typedef short s8v  __attribute__((ext_vector_type(8)));   // 8 bf16 (raw bits) = 4 VGPRs
typedef float f4v  __attribute__((ext_vector_type(4)));   // MFMA accumulator
typedef unsigned short u16x4 __attribute__((ext_vector_type(4)));

static __device__ __forceinline__ unsigned short f2bf(float f) {
  union { float f; unsigned u; } v; v.f = f;
  unsigned r = v.u + 0x7fffu + ((v.u >> 16) & 1u);   // round-to-nearest-even
  return (unsigned short)(r >> 16);
}
static __device__ __forceinline__ float bf2f(unsigned short h) {
  union { unsigned u; float f; } v; v.u = ((unsigned)h) << 16; return v.f;
}

// ---- int degree count (CSR) ----
__global__ void counti_k(const int* __restrict__ idx, int* __restrict__ cnt, int n) {
  int t = blockIdx.x * blockDim.x + threadIdx.x;
  if (t < n) atomicAdd(&cnt[idx[t]], 1);
}

// ---- graph boundaries via binary search in SORTED batch: gb[g] = lower_bound(g) ----
__global__ void bounds_k(const int* __restrict__ batch, int* __restrict__ gb) {
  int g = threadIdx.x;
  if (g > NG) return;
  int lo = 0, hi = NND;
  while (lo < hi) {
    int mid = (lo + hi) >> 1;
    if (batch[mid] < g) lo = mid + 1; else hi = mid;
  }
  gb[g] = lo;
}

// ---- 3-stage grid scan of cnt[NND] -> offs (exclusive), cur, offs[NND]=total ----
__global__ __launch_bounds__(256) void bsum_k(const int* __restrict__ cnt,
                                              int* __restrict__ bsum) {
  __shared__ int s[256];
  int i = blockIdx.x * 256 + threadIdx.x;
  s[threadIdx.x] = (i < NND) ? cnt[i] : 0;
  __syncthreads();
  for (int off = 128; off > 0; off >>= 1) {
    if (threadIdx.x < off) s[threadIdx.x] += s[threadIdx.x + off];
    __syncthreads();
  }
  if (threadIdx.x == 0) bsum[blockIdx.x] = s[0];
}

__global__ __launch_bounds__(256) void bscan_k(const int* __restrict__ bsum,
                                               int* __restrict__ boff,
                                               int* __restrict__ offs) {
  __shared__ int s[256];
  int t = threadIdx.x;
  s[t] = (t < NBLK) ? bsum[t] : 0;
  __syncthreads();
  for (int off = 1; off < 256; off <<= 1) {   // inclusive Hillis-Steele
    int v = (t >= off) ? s[t - off] : 0;
    __syncthreads();
    s[t] += v;
    __syncthreads();
  }
  if (t < NBLK) boff[t] = (t == 0) ? 0 : s[t - 1];
  if (t == NBLK - 1) offs[NND] = s[t];        // grand total
}

__global__ __launch_bounds__(256) void escan_k(const int* __restrict__ cnt,
                                               const int* __restrict__ boff,
                                               int* __restrict__ offs,
                                               int* __restrict__ cur) {
  __shared__ int s[256];
  int i = blockIdx.x * 256 + threadIdx.x;
  int t = threadIdx.x;
  int v = (i < NND) ? cnt[i] : 0;
  s[t] = v;
  __syncthreads();
  for (int off = 1; off < 256; off <<= 1) {   // inclusive Hillis-Steele
    int u = (t >= off) ? s[t - off] : 0;
    __syncthreads();
    s[t] += u;
    __syncthreads();
  }
  if (i < NND) {
    int excl = s[t] - v + boff[blockIdx.x];   // inclusive - self = exclusive
    offs[i] = excl;
    cur[i]  = excl;
  }
}

// ---- CSR fill: csr[pos] = src for edges grouped by dst ----
__global__ void fill_k(const int* __restrict__ src, const int* __restrict__ dst,
                       int* __restrict__ cur, int* __restrict__ csr) {
  int e = blockIdx.x * blockDim.x + threadIdx.x;
  if (e >= NED) return;
  int d = dst[e];
  int pos = atomicAdd(&cur[d], 1);
  csr[pos] = src[e];
}

// ---- fp32 -> bf16 conversion (layer-0 input) ----
__global__ void cvt_k(const float* __restrict__ in, unsigned short* __restrict__ out) {
  int t = blockIdx.x * blockDim.x + threadIdx.x;   // one float4 chunk; NND*32 total
  if (t >= NND * 32) return;
  float4 v = reinterpret_cast<const float4*>(in)[t];
  u16x4 o;
  o.x = f2bf(v.x); o.y = f2bf(v.y); o.z = f2bf(v.z); o.w = f2bf(v.w);
  reinterpret_cast<u16x4*>(out)[t] = o;
}

// ---- all 8 weight transposes+converts in ONE launch: WT[n*128+k]=bf16(W[k*128+n]) ----
struct WPtrs { const float* w[8]; unsigned short* wt[8]; };
__global__ void wcvt8_k(WPtrs p) {
  int t = blockIdx.x * blockDim.x + threadIdx.x;   // 8 * 16384 total
  if (t >= 8 * CD * CD) return;
  int m = t >> 14, r = t & (CD * CD - 1);
  int n = r >> 7, k = r & 127;
  p.wt[m][r] = f2bf(p.w[m][k * CD + n]);
}

// ---- CSR gather-reduce: ab[n] = bf16( mean_{e in in(n)} xb[csr[e]] ) ----
// One 32-lane team per dst node; lane owns 4 channels. Edge loop unrolled x4
// for 4 outstanding 8B gathers per team (latency hiding).
__global__ __launch_bounds__(256) void agg_k(const unsigned short* __restrict__ xb,
                                             const int* __restrict__ csr,
                                             const int* __restrict__ offs,
                                             unsigned short* __restrict__ ab) {
  const int team = (blockIdx.x * 256 + threadIdx.x) >> 5;   // == node id
  const int lane = threadIdx.x & 31;
  const int e0 = offs[team], e1 = offs[team + 1];
  const unsigned short* base = xb + lane * 4;
  float a0 = 0.f, a1 = 0.f, a2 = 0.f, a3 = 0.f;
  int e = e0;
  for (; e + 4 <= e1; e += 4) {
    int s0 = csr[e], s1 = csr[e + 1], s2 = csr[e + 2], s3 = csr[e + 3];
    u16x4 v0 = *reinterpret_cast<const u16x4*>(base + (size_t)s0 * CD);
    u16x4 v1 = *reinterpret_cast<const u16x4*>(base + (size_t)s1 * CD);
    u16x4 v2 = *reinterpret_cast<const u16x4*>(base + (size_t)s2 * CD);
    u16x4 v3 = *reinterpret_cast<const u16x4*>(base + (size_t)s3 * CD);
    a0 += bf2f(v0.x) + bf2f(v1.x) + bf2f(v2.x) + bf2f(v3.x);
    a1 += bf2f(v0.y) + bf2f(v1.y) + bf2f(v2.y) + bf2f(v3.y);
    a2 += bf2f(v0.z) + bf2f(v1.z) + bf2f(v2.z) + bf2f(v3.z);
    a3 += bf2f(v0.w) + bf2f(v1.w) + bf2f(v2.w) + bf2f(v3.w);
  }
  for (; e < e1; ++e) {
    int s0 = csr[e];
    u16x4 v0 = *reinterpret_cast<const u16x4*>(base + (size_t)s0 * CD);
    a0 += bf2f(v0.x); a1 += bf2f(v0.y); a2 += bf2f(v0.z); a3 += bf2f(v0.w);
  }
  const float invd = 1.0f / fmaxf((float)(e1 - e0), 1.0f);
  u16x4 o;
  o.x = f2bf(a0 * invd); o.y = f2bf(a1 * invd);
  o.z = f2bf(a2 * invd); o.w = f2bf(a3 * invd);
  *reinterpret_cast<u16x4*>(ab + (size_t)team * CD + lane * 4) = o;
}

// ---- fused: h = relu(ab @ Wl + xb @ Wr + bias); writes fp32 h and bf16 h ----
// Per block: 64 node rows x 128 cols. Per wave: 16 rows, 8 col-tiles of 16.
// MFMA 16x16x32 bf16; A frag: m=lane&15, k=quad*8+j; B frag from WT[n][k]:
// n=lane&15, k=quad*8+j; C/D: col=lane&15, row=quad*4+r (m89/m91-verified).
__global__ __launch_bounds__(256) void gemm_k(
    const unsigned short* __restrict__ ab, const unsigned short* __restrict__ xb,
    const unsigned short* __restrict__ WlT, const unsigned short* __restrict__ WrT,
    const float* __restrict__ bias, float* __restrict__ hf,
    unsigned short* __restrict__ hb) {
  const int wave = threadIdx.x >> 6;
  const int lane = threadIdx.x & 63;
  const int quad = lane >> 4;
  const int l16  = lane & 15;
  const int m0   = blockIdx.x * 64 + wave * 16;

  const int rowA  = m0 + l16;
  const int rowAc = rowA < NND ? rowA : NND - 1;   // clamp loads; stores are guarded

  s8v aA[4], aX[4];
#pragma unroll
  for (int kk = 0; kk < 4; ++kk) {
    size_t off = (size_t)rowAc * CD + kk * 32 + quad * 8;
    aA[kk] = *reinterpret_cast<const s8v*>(ab + off);
    aX[kk] = *reinterpret_cast<const s8v*>(xb + off);
  }

  f4v accL[8] = {};
  f4v accR[8] = {};

#pragma unroll
  for (int nt = 0; nt < 8; ++nt) {
    const int n = nt * 16 + l16;
#pragma unroll
    for (int kk = 0; kk < 4; ++kk) {
      size_t woff = (size_t)n * CD + kk * 32 + quad * 8;
      s8v bL = *reinterpret_cast<const s8v*>(WlT + woff);
      s8v bR = *reinterpret_cast<const s8v*>(WrT + woff);
      accL[nt] = __builtin_amdgcn_mfma_f32_16x16x32_bf16(aA[kk], bL, accL[nt], 0, 0, 0);
      accR[nt] = __builtin_amdgcn_mfma_f32_16x16x32_bf16(aX[kk], bR, accR[nt], 0, 0, 0);
    }
  }

#pragma unroll
  for (int nt = 0; nt < 8; ++nt) {
    const int col = nt * 16 + l16;
    const float bv = bias[col];
#pragma unroll
    for (int r = 0; r < 4; ++r) {
      int row = m0 + quad * 4 + r;
      if (row < NND) {
        float v = accL[nt][r] + accR[nt][r] + bv;
        v = fmaxf(v, 0.0f);
        hf[(size_t)row * CD + col] = v;
        hb[(size_t)row * CD + col] = f2bf(v);
      }
    }
  }
}

// ---- mean-pool: 32-row chunks, one thread per channel, boundary-flush atomics.
// batch is SORTED; common case = whole chunk inside one graph (branch-free sum). ----
__global__ __launch_bounds__(128) void pool3_k(const float* __restrict__ h,
                                               const int* __restrict__ batch,
                                               float* __restrict__ pooled) {
  const int c  = threadIdx.x;
  const int r0 = blockIdx.x * 32;
  const int rend = (r0 + 32 < NND) ? r0 + 32 : NND;
  const int g0 = batch[r0];
  const int g1 = batch[rend - 1];
  if (g0 == g1) {
    float acc = 0.f;
#pragma unroll
    for (int i = 0; i < 32; ++i) {
      int row = r0 + i;
      if (row < rend) acc += h[(size_t)row * CD + c];
    }
    atomicAdd(&pooled[g0 * CD + c], acc);
  } else {
    float acc = 0.f;
    int gcur = g0;
    for (int row = r0; row < rend; ++row) {
      int g = batch[row];
      if (g != gcur) {
        atomicAdd(&pooled[gcur * CD + c], acc);
        acc = 0.f; gcur = g;
      }
      acc += h[(size_t)row * CD + c];
    }
    atomicAdd(&pooled[gcur * CD + c], acc);
  }
}

// ---- classifier: out[g] = sigmoid(dot(pooled[g]/cnt, Wc) + bc) ----
__global__ void final_k(const float* __restrict__ pooled, const int* __restrict__ gb,
                        const float* __restrict__ Wc, const float* __restrict__ bc,
                        float* __restrict__ out) {
  int g = blockIdx.x;
  int lane = threadIdx.x;
  float part = pooled[g * CD + lane] * Wc[lane] +
               pooled[g * CD + 64 + lane] * Wc[64 + lane];
#pragma unroll
  for (int off = 32; off > 0; off >>= 1) part += __shfl_down(part, off, 64);
  if (lane == 0) {
    float cnt = (float)(gb[g + 1] - gb[g]);
    float z = part / fmaxf(cnt, 1.0f) + bc[0];
    out[g] = 1.0f / (1.0f + expf(-z));
  }
}

extern "C" void kernel_launch(void* const* d_in, const int* in_sizes, int n_in,
                              void* d_out, int out_size, void* d_ws, size_t ws_size,
                              hipStream_t stream) {
  const float* x   = (const float*)d_in[0];
  const int*   ei  = (const int*)d_in[1];
  const int*   src = ei;             // edge_index[0]
  const int*   dst = ei + NED;       // edge_index[1]
  // d_in[2] = edge_weight: unused by the reference
  const int*   batch = (const int*)d_in[3];
  const float* Wc = (const float*)d_in[16];
  const float* bc = (const float*)d_in[17];
  float* out = (float*)d_out;

  char* w = (char*)d_ws;
  auto alloc = [&](size_t bytes) {
    char* p = w; w += (bytes + 255) & ~(size_t)255; return p;
  };
  int* cnti = (int*)alloc(NND * 4);
  int* offs = (int*)alloc((NND + 1) * 4);
  int* cur  = (int*)alloc(NND * 4);
  int* csr  = (int*)alloc((size_t)NED * 4);
  int* gb   = (int*)alloc((NG + 1) * 4);
  int* bsum = (int*)alloc(256 * 4);
  int* boff = (int*)alloc(256 * 4);
  float* hA = (float*)alloc((size_t)NND * CD * 4);              // fp32 layer features
  unsigned short* xb0 = (unsigned short*)alloc((size_t)NND * CD * 2);
  unsigned short* xb1 = (unsigned short*)alloc((size_t)NND * CD * 2);
  unsigned short* ab  = (unsigned short*)alloc((size_t)NND * CD * 2);
  WPtrs wp;
  for (int i = 0; i < 4; ++i) {
    wp.w[2 * i]     = (const float*)d_in[4 + 3 * i];      // Wl{i+1}
    wp.w[2 * i + 1] = (const float*)d_in[5 + 3 * i];      // Wr{i+1}
  }
  for (int i = 0; i < 8; ++i) wp.wt[i] = (unsigned short*)alloc(CD * CD * 2);
  const float* bs[4] = {(const float*)d_in[6],  (const float*)d_in[9],
                        (const float*)d_in[12], (const float*)d_in[15]};
  float* pooled = (float*)alloc(NG * CD * 4);

  hipMemsetAsync(cnti, 0, NND * 4, stream);
  hipMemsetAsync(pooled, 0, NG * CD * 4, stream);

  // CSR build (per call; inputs are restored before every timed launch)
  counti_k<<<(NED + 255) / 256, 256, 0, stream>>>(dst, cnti, NED);
  bsum_k<<<NBLK, 256, 0, stream>>>(cnti, bsum);
  bscan_k<<<1, 256, 0, stream>>>(bsum, boff, offs);
  escan_k<<<NBLK, 256, 0, stream>>>(cnti, boff, offs, cur);
  fill_k<<<(NED + 255) / 256, 256, 0, stream>>>(src, dst, cur, csr);
  bounds_k<<<1, 128, 0, stream>>>(batch, gb);

  cvt_k<<<(NND * 32 + 255) / 256, 256, 0, stream>>>(x, xb0);
  wcvt8_k<<<(8 * CD * CD + 255) / 256, 256, 0, stream>>>(wp);

  unsigned short* xcur = xb0;
  unsigned short* xnxt = xb1;
  for (int l = 0; l < 4; ++l) {
    agg_k<<<(NND + 7) / 8, 256, 0, stream>>>(xcur, csr, offs, ab);
    gemm_k<<<(NND + 63) / 64, 256, 0, stream>>>(ab, xcur, wp.wt[2 * l], wp.wt[2 * l + 1],
                                                bs[l], hA, xnxt);
    unsigned short* t = xcur; xcur = xnxt; xnxt = t;
  }

  pool3_k<<<(NND + 31) / 32, 128, 0, stream>>>(hA, batch, pooled);
  final_k<<<NG, 64, 0, stream>>>(pooled, gb, Wc, bc, out);
}

// Round 6
// 399.706 us; speedup vs baseline: 12.3518x; 1.1405x over previous
//
#include <hip/hip_runtime.h>
#include <math.h>

// Problem constants (fixed by the reference)
#define NND 50000   // nodes
#define NED 600000  // edges
#define CD  128     // channels (in = hid = 128)
#define NG  64      // graphs
#define NBLK 196    // ceil(NND/256) scan blocks
#define GROWS 64    // rows per gemm block

typedef short s8v  __attribute__((ext_vector_type(8)));   // 8 bf16 (raw bits) = 4 VGPRs
typedef float f4v  __attribute__((ext_vector_type(4)));   // MFMA accumulator
typedef unsigned short u16x4 __attribute__((ext_vector_type(4)));

static __device__ __forceinline__ unsigned short f2bf(float f) {
  union { float f; unsigned u; } v; v.f = f;
  unsigned r = v.u + 0x7fffu + ((v.u >> 16) & 1u);   // round-to-nearest-even
  return (unsigned short)(r >> 16);
}
static __device__ __forceinline__ float bf2f(unsigned short h) {
  union { unsigned u; float f; } v; v.u = ((unsigned)h) << 16; return v.f;
}

// ---- int degree count (CSR) ----
__global__ void counti_k(const int* __restrict__ idx, int* __restrict__ cnt, int n) {
  int t = blockIdx.x * blockDim.x + threadIdx.x;
  if (t < n) atomicAdd(&cnt[idx[t]], 1);
}

// ---- graph boundaries via binary search in SORTED batch: gb[g] = lower_bound(g) ----
__global__ void bounds_k(const int* __restrict__ batch, int* __restrict__ gb) {
  int g = threadIdx.x;
  if (g > NG) return;
  int lo = 0, hi = NND;
  while (lo < hi) {
    int mid = (lo + hi) >> 1;
    if (batch[mid] < g) lo = mid + 1; else hi = mid;
  }
  gb[g] = lo;
}

// ---- 3-stage grid scan of cnt[NND] -> offs (exclusive), cur, offs[NND]=total ----
__global__ __launch_bounds__(256) void bsum_k(const int* __restrict__ cnt,
                                              int* __restrict__ bsum) {
  __shared__ int s[256];
  int i = blockIdx.x * 256 + threadIdx.x;
  s[threadIdx.x] = (i < NND) ? cnt[i] : 0;
  __syncthreads();
  for (int off = 128; off > 0; off >>= 1) {
    if (threadIdx.x < off) s[threadIdx.x] += s[threadIdx.x + off];
    __syncthreads();
  }
  if (threadIdx.x == 0) bsum[blockIdx.x] = s[0];
}

__global__ __launch_bounds__(256) void bscan_k(const int* __restrict__ bsum,
                                               int* __restrict__ boff,
                                               int* __restrict__ offs) {
  __shared__ int s[256];
  int t = threadIdx.x;
  s[t] = (t < NBLK) ? bsum[t] : 0;
  __syncthreads();
  for (int off = 1; off < 256; off <<= 1) {   // inclusive Hillis-Steele
    int v = (t >= off) ? s[t - off] : 0;
    __syncthreads();
    s[t] += v;
    __syncthreads();
  }
  if (t < NBLK) boff[t] = (t == 0) ? 0 : s[t - 1];
  if (t == NBLK - 1) offs[NND] = s[t];        // grand total
}

__global__ __launch_bounds__(256) void escan_k(const int* __restrict__ cnt,
                                               const int* __restrict__ boff,
                                               int* __restrict__ offs,
                                               int* __restrict__ cur) {
  __shared__ int s[256];
  int i = blockIdx.x * 256 + threadIdx.x;
  int t = threadIdx.x;
  int v = (i < NND) ? cnt[i] : 0;
  s[t] = v;
  __syncthreads();
  for (int off = 1; off < 256; off <<= 1) {   // inclusive Hillis-Steele
    int u = (t >= off) ? s[t - off] : 0;
    __syncthreads();
    s[t] += u;
    __syncthreads();
  }
  if (i < NND) {
    int excl = s[t] - v + boff[blockIdx.x];   // inclusive - self = exclusive
    offs[i] = excl;
    cur[i]  = excl;
  }
}

// ---- CSR fill: csr[pos] = src for edges grouped by dst ----
__global__ void fill_k(const int* __restrict__ src, const int* __restrict__ dst,
                       int* __restrict__ cur, int* __restrict__ csr) {
  int e = blockIdx.x * blockDim.x + threadIdx.x;
  if (e >= NED) return;
  int d = dst[e];
  int pos = atomicAdd(&cur[d], 1);
  csr[pos] = src[e];
}

// ---- fp32 -> bf16 conversion (layer-0 input) ----
__global__ void cvt_k(const float* __restrict__ in, unsigned short* __restrict__ out) {
  int t = blockIdx.x * blockDim.x + threadIdx.x;   // one float4 chunk; NND*32 total
  if (t >= NND * 32) return;
  float4 v = reinterpret_cast<const float4*>(in)[t];
  u16x4 o;
  o.x = f2bf(v.x); o.y = f2bf(v.y); o.z = f2bf(v.z); o.w = f2bf(v.w);
  reinterpret_cast<u16x4*>(out)[t] = o;
}

// ---- all 8 weight transposes+converts in ONE launch: WT[n*128+k]=bf16(W[k*128+n]) ----
struct WPtrs { const float* w[8]; unsigned short* wt[8]; };
__global__ void wcvt8_k(WPtrs p) {
  int t = blockIdx.x * blockDim.x + threadIdx.x;   // 8 * 16384 total
  if (t >= 8 * CD * CD) return;
  int m = t >> 14, r = t & (CD * CD - 1);
  int n = r >> 7, k = r & 127;
  p.wt[m][r] = f2bf(p.w[m][k * CD + n]);
}

// ---- CSR gather-reduce: ab[n] = bf16( mean_{e in in(n)} xb[csr[e]] ) ----
// One 32-lane team per dst node; lane owns 4 channels. Edge loop unrolled x4
// for 4 outstanding 8B gathers per team (latency hiding).
__global__ __launch_bounds__(256) void agg_k(const unsigned short* __restrict__ xb,
                                             const int* __restrict__ csr,
                                             const int* __restrict__ offs,
                                             unsigned short* __restrict__ ab) {
  const int team = (blockIdx.x * 256 + threadIdx.x) >> 5;   // == node id
  const int lane = threadIdx.x & 31;
  const int e0 = offs[team], e1 = offs[team + 1];
  const unsigned short* base = xb + lane * 4;
  float a0 = 0.f, a1 = 0.f, a2 = 0.f, a3 = 0.f;
  int e = e0;
  for (; e + 4 <= e1; e += 4) {
    int s0 = csr[e], s1 = csr[e + 1], s2 = csr[e + 2], s3 = csr[e + 3];
    u16x4 v0 = *reinterpret_cast<const u16x4*>(base + (size_t)s0 * CD);
    u16x4 v1 = *reinterpret_cast<const u16x4*>(base + (size_t)s1 * CD);
    u16x4 v2 = *reinterpret_cast<const u16x4*>(base + (size_t)s2 * CD);
    u16x4 v3 = *reinterpret_cast<const u16x4*>(base + (size_t)s3 * CD);
    a0 += bf2f(v0.x) + bf2f(v1.x) + bf2f(v2.x) + bf2f(v3.x);
    a1 += bf2f(v0.y) + bf2f(v1.y) + bf2f(v2.y) + bf2f(v3.y);
    a2 += bf2f(v0.z) + bf2f(v1.z) + bf2f(v2.z) + bf2f(v3.z);
    a3 += bf2f(v0.w) + bf2f(v1.w) + bf2f(v2.w) + bf2f(v3.w);
  }
  for (; e < e1; ++e) {
    int s0 = csr[e];
    u16x4 v0 = *reinterpret_cast<const u16x4*>(base + (size_t)s0 * CD);
    a0 += bf2f(v0.x); a1 += bf2f(v0.y); a2 += bf2f(v0.z); a3 += bf2f(v0.w);
  }
  const float invd = 1.0f / fmaxf((float)(e1 - e0), 1.0f);
  u16x4 o;
  o.x = f2bf(a0 * invd); o.y = f2bf(a1 * invd);
  o.z = f2bf(a2 * invd); o.w = f2bf(a3 * invd);
  *reinterpret_cast<u16x4*>(ab + (size_t)team * CD + lane * 4) = o;
}

// ---- fused: h = relu(ab @ Wl + xb @ Wr + bias) ----
// Wave w owns cols [w*32, w*32+32): its 16 B-frags (Wl+Wr, all K) live in
// registers, loaded ONCE per block. Both products accumulate into one acc.
// Block covers GROWS=64 rows (4 iters x 16). Layers 0-2 write hb (bf16) only;
// layer 3 writes hf (fp32) only — pass nullptr for the unused output.
// MFMA 16x16x32 bf16; A: m=lane&15,k=quad*8+j; B from WT[n][k]: n=lane&15;
// C/D: col=lane&15, row=quad*4+r (m89/m91-verified).
__global__ __launch_bounds__(256) void gemm2_k(
    const unsigned short* __restrict__ ab, const unsigned short* __restrict__ xb,
    const unsigned short* __restrict__ WlT, const unsigned short* __restrict__ WrT,
    const float* __restrict__ bias, float* __restrict__ hf,
    unsigned short* __restrict__ hb) {
  const int wave = threadIdx.x >> 6;
  const int lane = threadIdx.x & 63;
  const int quad = lane >> 4;
  const int l16  = lane & 15;

  s8v bL[2][4], bR[2][4];
#pragma unroll
  for (int nt = 0; nt < 2; ++nt) {
    const int n = wave * 32 + nt * 16 + l16;
#pragma unroll
    for (int kk = 0; kk < 4; ++kk) {
      size_t woff = (size_t)n * CD + kk * 32 + quad * 8;
      bL[nt][kk] = *reinterpret_cast<const s8v*>(WlT + woff);
      bR[nt][kk] = *reinterpret_cast<const s8v*>(WrT + woff);
    }
  }
  const float bv0 = bias[wave * 32 + l16];
  const float bv1 = bias[wave * 32 + 16 + l16];

  const int rbase = blockIdx.x * GROWS;
#pragma unroll
  for (int rt = 0; rt < GROWS / 16; ++rt) {
    const int m0 = rbase + rt * 16;
    if (m0 >= NND) break;
    const int rowA  = m0 + l16;
    const int rowAc = rowA < NND ? rowA : NND - 1;
    s8v aA[4], aX[4];
#pragma unroll
    for (int kk = 0; kk < 4; ++kk) {
      size_t off = (size_t)rowAc * CD + kk * 32 + quad * 8;
      aA[kk] = *reinterpret_cast<const s8v*>(ab + off);
      aX[kk] = *reinterpret_cast<const s8v*>(xb + off);
    }
    f4v acc0 = {}, acc1 = {};
#pragma unroll
    for (int kk = 0; kk < 4; ++kk) {
      acc0 = __builtin_amdgcn_mfma_f32_16x16x32_bf16(aA[kk], bL[0][kk], acc0, 0, 0, 0);
      acc0 = __builtin_amdgcn_mfma_f32_16x16x32_bf16(aX[kk], bR[0][kk], acc0, 0, 0, 0);
      acc1 = __builtin_amdgcn_mfma_f32_16x16x32_bf16(aA[kk], bL[1][kk], acc1, 0, 0, 0);
      acc1 = __builtin_amdgcn_mfma_f32_16x16x32_bf16(aX[kk], bR[1][kk], acc1, 0, 0, 0);
    }
#pragma unroll
    for (int r = 0; r < 4; ++r) {
      const int row = m0 + quad * 4 + r;
      if (row < NND) {
        const int c0 = wave * 32 + l16;
        float v0 = fmaxf(acc0[r] + bv0, 0.0f);
        float v1 = fmaxf(acc1[r] + bv1, 0.0f);
        if (hb) {
          hb[(size_t)row * CD + c0]      = f2bf(v0);
          hb[(size_t)row * CD + c0 + 16] = f2bf(v1);
        }
        if (hf) {
          hf[(size_t)row * CD + c0]      = v0;
          hf[(size_t)row * CD + c0 + 16] = v1;
        }
      }
    }
  }
}

// ---- mean-pool: 32-row chunks, one thread per channel, boundary-flush atomics.
// batch is SORTED; common case = whole chunk inside one graph (branch-free sum). ----
__global__ __launch_bounds__(128) void pool3_k(const float* __restrict__ h,
                                               const int* __restrict__ batch,
                                               float* __restrict__ pooled) {
  const int c  = threadIdx.x;
  const int r0 = blockIdx.x * 32;
  const int rend = (r0 + 32 < NND) ? r0 + 32 : NND;
  const int g0 = batch[r0];
  const int g1 = batch[rend - 1];
  if (g0 == g1) {
    float acc = 0.f;
#pragma unroll
    for (int i = 0; i < 32; ++i) {
      int row = r0 + i;
      if (row < rend) acc += h[(size_t)row * CD + c];
    }
    atomicAdd(&pooled[g0 * CD + c], acc);
  } else {
    float acc = 0.f;
    int gcur = g0;
    for (int row = r0; row < rend; ++row) {
      int g = batch[row];
      if (g != gcur) {
        atomicAdd(&pooled[gcur * CD + c], acc);
        acc = 0.f; gcur = g;
      }
      acc += h[(size_t)row * CD + c];
    }
    atomicAdd(&pooled[gcur * CD + c], acc);
  }
}

// ---- classifier: out[g] = sigmoid(dot(pooled[g]/cnt, Wc) + bc) ----
__global__ void final_k(const float* __restrict__ pooled, const int* __restrict__ gb,
                        const float* __restrict__ Wc, const float* __restrict__ bc,
                        float* __restrict__ out) {
  int g = blockIdx.x;
  int lane = threadIdx.x;
  float part = pooled[g * CD + lane] * Wc[lane] +
               pooled[g * CD + 64 + lane] * Wc[64 + lane];
#pragma unroll
  for (int off = 32; off > 0; off >>= 1) part += __shfl_down(part, off, 64);
  if (lane == 0) {
    float cnt = (float)(gb[g + 1] - gb[g]);
    float z = part / fmaxf(cnt, 1.0f) + bc[0];
    out[g] = 1.0f / (1.0f + expf(-z));
  }
}

extern "C" void kernel_launch(void* const* d_in, const int* in_sizes, int n_in,
                              void* d_out, int out_size, void* d_ws, size_t ws_size,
                              hipStream_t stream) {
  const float* x   = (const float*)d_in[0];
  const int*   ei  = (const int*)d_in[1];
  const int*   src = ei;             // edge_index[0]
  const int*   dst = ei + NED;       // edge_index[1]
  // d_in[2] = edge_weight: unused by the reference
  const int*   batch = (const int*)d_in[3];
  const float* Wc = (const float*)d_in[16];
  const float* bc = (const float*)d_in[17];
  float* out = (float*)d_out;

  char* w = (char*)d_ws;
  auto alloc = [&](size_t bytes) {
    char* p = w; w += (bytes + 255) & ~(size_t)255; return p;
  };
  int* cnti = (int*)alloc(NND * 4);
  int* offs = (int*)alloc((NND + 1) * 4);
  int* cur  = (int*)alloc(NND * 4);
  int* csr  = (int*)alloc((size_t)NED * 4);
  int* gb   = (int*)alloc((NG + 1) * 4);
  int* bsum = (int*)alloc(256 * 4);
  int* boff = (int*)alloc(256 * 4);
  float* hA = (float*)alloc((size_t)NND * CD * 4);              // fp32 final-layer feats
  unsigned short* xb0 = (unsigned short*)alloc((size_t)NND * CD * 2);
  unsigned short* xb1 = (unsigned short*)alloc((size_t)NND * CD * 2);
  unsigned short* ab  = (unsigned short*)alloc((size_t)NND * CD * 2);
  WPtrs wp;
  for (int i = 0; i < 4; ++i) {
    wp.w[2 * i]     = (const float*)d_in[4 + 3 * i];      // Wl{i+1}
    wp.w[2 * i + 1] = (const float*)d_in[5 + 3 * i];      // Wr{i+1}
  }
  for (int i = 0; i < 8; ++i) wp.wt[i] = (unsigned short*)alloc(CD * CD * 2);
  const float* bs[4] = {(const float*)d_in[6],  (const float*)d_in[9],
                        (const float*)d_in[12], (const float*)d_in[15]};
  float* pooled = (float*)alloc(NG * CD * 4);

  hipMemsetAsync(cnti, 0, NND * 4, stream);
  hipMemsetAsync(pooled, 0, NG * CD * 4, stream);

  // CSR build (per call; inputs are restored before every timed launch)
  counti_k<<<(NED + 255) / 256, 256, 0, stream>>>(dst, cnti, NED);
  bsum_k<<<NBLK, 256, 0, stream>>>(cnti, bsum);
  bscan_k<<<1, 256, 0, stream>>>(bsum, boff, offs);
  escan_k<<<NBLK, 256, 0, stream>>>(cnti, boff, offs, cur);
  fill_k<<<(NED + 255) / 256, 256, 0, stream>>>(src, dst, cur, csr);
  bounds_k<<<1, 128, 0, stream>>>(batch, gb);

  cvt_k<<<(NND * 32 + 255) / 256, 256, 0, stream>>>(x, xb0);
  wcvt8_k<<<(8 * CD * CD + 255) / 256, 256, 0, stream>>>(wp);

  unsigned short* xcur = xb0;
  unsigned short* xnxt = xb1;
  const int ggrid = (NND + GROWS - 1) / GROWS;
  for (int l = 0; l < 4; ++l) {
    agg_k<<<(NND + 7) / 8, 256, 0, stream>>>(xcur, csr, offs, ab);
    if (l < 3) {
      gemm2_k<<<ggrid, 256, 0, stream>>>(ab, xcur, wp.wt[2 * l], wp.wt[2 * l + 1],
                                         bs[l], nullptr, xnxt);
    } else {
      gemm2_k<<<ggrid, 256, 0, stream>>>(ab, xcur, wp.wt[2 * l], wp.wt[2 * l + 1],
                                         bs[l], hA, nullptr);
    }
    unsigned short* t = xcur; xcur = xnxt; xnxt = t;
  }

  pool3_k<<<(NND + 31) / 32, 128, 0, stream>>>(hA, batch, pooled);
  final_k<<<NG, 64, 0, stream>>>(pooled, gb, Wc, bc, out);
}